// Round 10
// baseline (250.524 us; speedup 1.0000x reference)
//
#include <hip/hip_runtime.h>

typedef unsigned short ushort_t;
typedef unsigned char uchar_t;
typedef __bf16 bf16x8 __attribute__((ext_vector_type(8)));
typedef float f32x4 __attribute__((ext_vector_type(4)));

__device__ __forceinline__ ushort_t f2bf(float f) {
  unsigned u = __float_as_uint(f);
  u += 0x7fff + ((u >> 16) & 1);
  return (ushort_t)(u >> 16);
}

__device__ __forceinline__ uchar_t f2fp8(float v) {
  unsigned w = __builtin_amdgcn_cvt_pk_fp8_f32(v, v, 0u, false);
  return (uchar_t)(w & 0xff);
}

__device__ __forceinline__ void gload16(const void* g, void* l) {
  __builtin_amdgcn_global_load_lds(
      (const __attribute__((address_space(1))) unsigned int*)g,
      (__attribute__((address_space(3))) unsigned int*)l, 16, 0, 0);
}

// ---- weights -> fp8 (qk,v) / bf16 (o), pack qk bias, zero stats2 + l ----
__global__ __launch_bounds__(256) void cvt_weights(
    const float* __restrict__ wq, const float* __restrict__ wk,
    const float* __restrict__ wv, const float* __restrict__ wo,
    const float* __restrict__ bq, const float* __restrict__ bk,
    uchar_t* __restrict__ wqk8, uchar_t* __restrict__ wv8,
    ushort_t* __restrict__ wob, float* __restrict__ qkbias,
    float* __restrict__ stats2, float* __restrict__ l) {
  int b = blockIdx.x, t = threadIdx.x;
  if (b < 1024) {
    int i = b * 256 + t;  // 262144 per matrix
    wqk8[i]          = f2fp8(wq[i]);
    wqk8[262144 + i] = f2fp8(wk[i]);
    wv8[i]           = f2fp8(wv[i]);
    wob[i]           = f2bf(wo[i]);
  } else if (b < 1028) {
    int j = (b - 1024) * 256 + t;  // 0..1023
    qkbias[j] = (j < 512) ? bq[j] : bk[j - 512];
  } else if (b == 1028) {
    if (t < 128) stats2[t] = 0.f;
  } else {
    l[(b - 1029) * 256 + t] = 0.f;  // 32 blocks -> 8192 row sums
  }
}

// ---------------- group norm partial stats: 4 blocks per (b,g) ----------------
__global__ __launch_bounds__(256) void gn_stats_partial(const float* __restrict__ x,
                                                        float* __restrict__ stats2) {
  int bg = blockIdx.x >> 2, q = blockIdx.x & 3;
  const float4* p = (const float4*)(x + (size_t)bg * 65536 + q * 16384);
  float s = 0.f, ss = 0.f;
  for (int i = threadIdx.x; i < 4096; i += 256) {
    float4 v = p[i];
    s += v.x + v.y + v.z + v.w;
    ss += v.x * v.x + v.y * v.y + v.z * v.z + v.w * v.w;
  }
  for (int off = 32; off; off >>= 1) {
    s += __shfl_xor(s, off, 64);
    ss += __shfl_xor(ss, off, 64);
  }
  __shared__ float sh[8];
  int wave = threadIdx.x >> 6, lane = threadIdx.x & 63;
  if (lane == 0) { sh[wave] = s; sh[4 + wave] = ss; }
  __syncthreads();
  if (threadIdx.x == 0) {
    atomicAdd(&stats2[bg * 2], sh[0] + sh[1] + sh[2] + sh[3]);
    atomicAdd(&stats2[bg * 2 + 1], sh[4] + sh[5] + sh[6] + sh[7]);
  }
}

__global__ __launch_bounds__(64) void gn_finalize(const float* __restrict__ stats2,
                                                  float* __restrict__ stats) {
  int t = threadIdx.x;  // 64 groups total
  float s = stats2[t * 2], ss = stats2[t * 2 + 1];
  float mean = s * (1.f / 65536.f);
  float var = ss * (1.f / 65536.f) - mean * mean;
  stats[t * 2] = mean;
  stats[t * 2 + 1] = rsqrtf(var + 1e-6f);
}

// -------- GN apply + transpose: x (b,c,n) -> hn8 (b,n,c) fp8 e4m3 --------
__global__ __launch_bounds__(256) void gn_apply(
    const float* __restrict__ x, const float* __restrict__ gamma,
    const float* __restrict__ beta, const float* __restrict__ stats,
    uchar_t* __restrict__ hn8) {
  __shared__ float T[32][33];
  int i0 = blockIdx.x * 32, c0 = blockIdx.y * 32, b = blockIdx.z;
  int tx = threadIdx.x, ty = threadIdx.y;  // (32,8)
#pragma unroll
  for (int k = 0; k < 4; k++) {
    int cl = ty + k * 8;
    int c = c0 + cl;
    int bg = (b * 32 + (c >> 4)) * 2;
    float mean = stats[bg], rstd = stats[bg + 1];
    float v = x[((size_t)(b * 512 + c)) * 4096 + i0 + tx];
    T[cl][tx] = (v - mean) * rstd * gamma[c] + beta[c];
  }
  __syncthreads();
  int t = ty * 32 + tx;
  int il = t >> 3, cu = (t & 7) * 4;  // spatial row, starting channel
  unsigned w = __builtin_amdgcn_cvt_pk_fp8_f32(T[cu][il], T[cu + 1][il], 0u, false);
  w = __builtin_amdgcn_cvt_pk_fp8_f32(T[cu + 2][il], T[cu + 3][il], w, true);
  *(unsigned*)&hn8[((size_t)b * 4096 + i0 + il) * 512 + c0 + cu] = w;
}

// ---------------- bf16 C = A * B^T GEMM (proj only), round-5 engine -----------
template <int BN>
__global__ __launch_bounds__(256) void gemm_abt(
    const ushort_t* __restrict__ A, long long sA, int lda,
    const ushort_t* __restrict__ B, long long sB, int ldb,
    int K, int N, int ldc,
    ushort_t* __restrict__ outB, long long sC,
    const float* __restrict__ bias, int bias_mode, float scale,
    float* __restrict__ outF, const float* __restrict__ resid,
    float* __restrict__ rowsum, const float* __restrict__ colscale,
    int swiz, int omode) {
  constexpr int CPW = (8 + BN / 16) / 4;
  constexpr int SB = (128 + BN) * 32;
  constexpr int MI = (BN == 128) ? 4 : 2;
  constexpr int NI = 4;
  __shared__ __align__(16) ushort_t Ls[2][SB];

  int bx = blockIdx.x, by = blockIdx.y, bz = blockIdx.z;
  if (swiz) {
    unsigned nx = gridDim.x, ny = gridDim.y;
    unsigned id = (blockIdx.z * ny + blockIdx.y) * nx + blockIdx.x;
    unsigned pb8 = (nx * ny) >> 3;
    unsigned c = id & 7, j = id >> 3;
    bz = j / pb8;
    unsigned jb = j - bz * pb8;
    unsigned jy = jb / nx;
    by = c * (ny >> 3) + jy;
    bx = jb - jy * nx;
  }

  int m0 = by * 128, n0 = bx * BN;
  int t = threadIdx.x;
  int lane = t & 63;
  int quad = lane >> 4, l16 = lane & 15;
  int wave = t >> 6;
  int wm = (BN == 128) ? (wave >> 1) * 64 : wave * 32;
  int wn = (BN == 128) ? (wave & 1) * 64 : 0;

  f32x4 acc[MI][NI];
#pragma unroll
  for (int i = 0; i < MI; i++)
#pragma unroll
    for (int j = 0; j < NI; j++)
#pragma unroll
      for (int r = 0; r < 4; r++) acc[i][j][r] = 0.f;

  const ushort_t* gp[CPW];
  int lofs[CPW];
  int crow = lane >> 2, skoff = (lane & 3) * 8;
#pragma unroll
  for (int i = 0; i < CPW; i++) {
    int c = wave * CPW + i;
    if (c < 8) {
      gp[i] = A + (size_t)bz * sA + (size_t)(m0 + c * 16 + crow) * lda + skoff;
      lofs[i] = c * 1024 + lane * 16;
    } else {
      int slot = (c - 8) * 16 + crow;
      int arow = (slot & ~63) + ((slot & 15) * 4) + ((slot & 63) >> 4);
      gp[i] = B + (size_t)bz * sB + (size_t)(n0 + arow) * ldb + skoff;
      lofs[i] = 8192 + (c - 8) * 1024 + lane * 16;
    }
  }
  char* lbase = (char*)&Ls[0][0];

#pragma unroll
  for (int i = 0; i < CPW; i++) gload16(gp[i], lbase + lofs[i]);

  for (int k0 = 0; k0 < K; k0 += 32) {
    int p = (k0 >> 5) & 1;
    __syncthreads();
    if (k0 + 32 < K) {
      int pofs = (p ^ 1) * (SB * 2);
#pragma unroll
      for (int i = 0; i < CPW; i++) gload16(gp[i] + k0 + 32, lbase + pofs + lofs[i]);
    }
    bf16x8 af[MI], bfr[NI];
#pragma unroll
    for (int i = 0; i < MI; i++)
      af[i] = *(const bf16x8*)&Ls[p][(wm + i * 16 + l16) * 32 + quad * 8];
#pragma unroll
    for (int j = 0; j < NI; j++)
      bfr[j] = *(const bf16x8*)&Ls[p][4096 + (wn + j * 16 + l16) * 32 + quad * 8];
#pragma unroll
    for (int mi = 0; mi < MI; mi++)
#pragma unroll
      for (int ni = 0; ni < NI; ni++)
        acc[mi][ni] = __builtin_amdgcn_mfma_f32_16x16x32_bf16(af[mi], bfr[ni], acc[mi][ni], 0, 0, 0);
  }

  size_t cbase = (size_t)bz * sC;
  int gnb = n0 + wn + l16 * 4;
  float cs4[4] = {1.f, 1.f, 1.f, 1.f};
  if (colscale) {
    float4 c4 = *(const float4*)&colscale[(size_t)bz * N + gnb];
    cs4[0] = 1.f / c4.x; cs4[1] = 1.f / c4.y; cs4[2] = 1.f / c4.z; cs4[3] = 1.f / c4.w;
  }
  float b4[4] = {0.f, 0.f, 0.f, 0.f};
  if (bias_mode == 2) {
    float4 t4 = *(const float4*)&bias[gnb];
    b4[0] = t4.x; b4[1] = t4.y; b4[2] = t4.z; b4[3] = t4.w;
  }
#pragma unroll
  for (int mi = 0; mi < MI; mi++) {
#pragma unroll
    for (int r = 0; r < 4; r++) {
      int m = m0 + wm + mi * 16 + quad * 4 + r;
      float rbias = (bias_mode == 1) ? bias[m] : 0.f;
      float v4[4];
#pragma unroll
      for (int ni = 0; ni < NI; ni++) {
        float val = acc[mi][ni][r];
        if (colscale) val *= cs4[ni];
        val += (bias_mode == 2) ? b4[ni] : rbias;
        val *= scale;
        v4[ni] = val;
      }
      size_t idx = cbase + (size_t)m * ldc + gnb;
      if (omode == 1) {
        float4 rv = *(const float4*)&resid[idx];
        float4 ov = make_float4(v4[0] + rv.x, v4[1] + rv.y, v4[2] + rv.z, v4[3] + rv.w);
        *(float4*)&outF[idx] = ov;
      } else {
        unsigned lo = (unsigned)f2bf(v4[0]) | ((unsigned)f2bf(v4[1]) << 16);
        unsigned hi = (unsigned)f2bf(v4[2]) | ((unsigned)f2bf(v4[3]) << 16);
        *(uint2*)&outB[idx] = make_uint2(lo, hi);
      }
    }
  }
}

// ---------------- fp8 C = A * B^T GEMM, 128 x BN tile, BK=64 ------------------
// Seg-transposed DMA staging (conflict-free fragment reads). Packed epilogue.
// omode: 0 = bf16 out; 2 = exp(scale*acc)/16 -> fp8 + rowsum; 3 = fp8 + bias.
template <int BN>
__global__ __launch_bounds__(256) void gemm_fp8(
    const uchar_t* __restrict__ A, long long sA, int lda,
    const uchar_t* __restrict__ B, long long sB, int ldb,
    int K, int ldc,
    void* __restrict__ outp, long long sC,
    const float* __restrict__ bias, int bias_mode, float scale,
    float* __restrict__ rowsum, int swiz, int omode) {
  constexpr int CPW = (8 + BN / 16) / 4;
  constexpr int SBB = (128 + BN) * 64;   // bytes per buffer
  constexpr int MI = (BN == 128) ? 4 : 2;
  constexpr int NI = 4;
  __shared__ __align__(16) uchar_t Ls[2][SBB];

  int bx = blockIdx.x, by = blockIdx.y, bz = blockIdx.z;
  if (swiz) {
    unsigned nx = gridDim.x, ny = gridDim.y;
    unsigned id = (blockIdx.z * ny + blockIdx.y) * nx + blockIdx.x;
    unsigned pb8 = (nx * ny) >> 3;
    unsigned c = id & 7, j = id >> 3;
    bz = j / pb8;
    unsigned jb = j - bz * pb8;
    unsigned jy = jb / nx;
    by = c * (ny >> 3) + jy;
    bx = jb - jy * nx;
  }

  int m0 = by * 128, n0 = bx * BN;
  int t = threadIdx.x;
  int lane = t & 63;
  int quad = lane >> 4, l16 = lane & 15;
  int wave = t >> 6;
  int wm = (BN == 128) ? (wave >> 1) * 64 : wave * 32;
  int wn = (BN == 128) ? (wave & 1) * 64 : 0;

  f32x4 acc[MI][NI];
#pragma unroll
  for (int i = 0; i < MI; i++)
#pragma unroll
    for (int j = 0; j < NI; j++)
#pragma unroll
      for (int r = 0; r < 4; r++) acc[i][j][r] = 0.f;

  // seg-transposed staging: lane i -> row i&15, 16B-seg i>>4
  const uchar_t* gp[CPW];
  int lofs[CPW];
  int r16 = lane & 15, sseg = (lane >> 4) * 16;
#pragma unroll
  for (int i = 0; i < CPW; i++) {
    int c = wave * CPW + i;
    if (c < 8) {
      gp[i] = A + (size_t)bz * sA + (size_t)(m0 + c * 16 + r16) * lda + sseg;
      lofs[i] = c * 1024 + lane * 16;
    } else {
      int slot = (c - 8) * 16 + r16;
      int arow = (slot & ~63) + ((slot & 15) * 4) + ((slot & 63) >> 4);
      gp[i] = B + (size_t)bz * sB + (size_t)(n0 + arow) * ldb + sseg;
      lofs[i] = 8192 + (c - 8) * 1024 + lane * 16;
    }
  }
  char* lbase = (char*)&Ls[0][0];

#pragma unroll
  for (int i = 0; i < CPW; i++) gload16(gp[i], lbase + lofs[i]);

  int vbase = l16 * 16 + (quad >> 1) * 256 + (quad & 1) * 8;
  for (int k0 = 0; k0 < K; k0 += 64) {
    int p = (k0 >> 6) & 1;
    __syncthreads();
    if (k0 + 64 < K) {
      int pofs = (p ^ 1) * SBB;
#pragma unroll
      for (int i = 0; i < CPW; i++) gload16(gp[i] + k0 + 64, lbase + pofs + lofs[i]);
    }
    const uchar_t* Lp = &Ls[p][0];
    long long af[2][MI], bfv[2][NI];
#pragma unroll
    for (int s = 0; s < 2; s++) {
#pragma unroll
      for (int i = 0; i < MI; i++)
        af[s][i] = *(const long long*)&Lp[wm * 64 + i * 1024 + s * 512 + vbase];
#pragma unroll
      for (int j = 0; j < NI; j++)
        bfv[s][j] = *(const long long*)&Lp[8192 + wn * 64 + j * 1024 + s * 512 + vbase];
    }
#pragma unroll
    for (int s = 0; s < 2; s++)
#pragma unroll
      for (int mi = 0; mi < MI; mi++)
#pragma unroll
        for (int ni = 0; ni < NI; ni++)
          acc[mi][ni] = __builtin_amdgcn_mfma_f32_16x16x32_fp8_fp8(af[s][mi], bfv[s][ni], acc[mi][ni], 0, 0, 0);
  }

  size_t cbase = (size_t)bz * sC;
  int gnb = n0 + wn + l16 * 4;
  float b4[4] = {0.f, 0.f, 0.f, 0.f};
  if (bias_mode == 2) {
    float4 t4 = *(const float4*)&bias[gnb];
    b4[0] = t4.x; b4[1] = t4.y; b4[2] = t4.z; b4[3] = t4.w;
  }
#pragma unroll
  for (int mi = 0; mi < MI; mi++) {
#pragma unroll
    for (int r = 0; r < 4; r++) {
      int m = m0 + wm + mi * 16 + quad * 4 + r;
      float rbias = (bias_mode == 1) ? bias[m] : 0.f;
      float v4[4];
      float rs = 0.f;
#pragma unroll
      for (int ni = 0; ni < NI; ni++) {
        float val = acc[mi][ni][r];
        val += (bias_mode == 2) ? b4[ni] : rbias;
        if (omode == 2) { val = __expf(val * scale) * 0.0625f; rs += val; }
        v4[ni] = val;
      }
      size_t idx = cbase + (size_t)m * ldc + gnb;
      if (omode == 0) {
        unsigned lo = (unsigned)f2bf(v4[0]) | ((unsigned)f2bf(v4[1]) << 16);
        unsigned hi = (unsigned)f2bf(v4[2]) | ((unsigned)f2bf(v4[3]) << 16);
        *(uint2*)&((ushort_t*)outp)[idx] = make_uint2(lo, hi);
      } else {
        unsigned w = __builtin_amdgcn_cvt_pk_fp8_f32(v4[0], v4[1], 0u, false);
        w = __builtin_amdgcn_cvt_pk_fp8_f32(v4[2], v4[3], w, true);
        *(unsigned*)&((uchar_t*)outp)[idx] = w;
      }
      if (omode == 2) {
        rs += __shfl_xor(rs, 1, 64);
        rs += __shfl_xor(rs, 2, 64);
        rs += __shfl_xor(rs, 4, 64);
        rs += __shfl_xor(rs, 8, 64);
        if (l16 == 0) atomicAdd(&rowsum[(size_t)bz * 4096 + m], rs);
      }
    }
  }
}

extern "C" void kernel_launch(void* const* d_in, const int* in_sizes, int n_in,
                              void* d_out, int out_size, void* d_ws, size_t ws_size,
                              hipStream_t stream) {
  const float* x     = (const float*)d_in[0];
  const float* gamma = (const float*)d_in[1];
  const float* beta  = (const float*)d_in[2];
  const float* wq    = (const float*)d_in[3];
  const float* bq    = (const float*)d_in[4];
  const float* wk    = (const float*)d_in[5];
  const float* bk    = (const float*)d_in[6];
  const float* wv    = (const float*)d_in[7];
  const float* bv    = (const float*)d_in[8];
  const float* wo    = (const float*)d_in[9];
  const float* bo    = (const float*)d_in[10];
  float* out = (float*)d_out;

  // workspace layout (byte offsets)
  uchar_t* base = (uchar_t*)d_ws;
  uchar_t* wqk8 = base;                         // 1024x512 fp8
  uchar_t* wv8  = base + 524288;                // 512x512 fp8
  ushort_t* wob = (ushort_t*)(base + 786432);   // 512x512 bf16
  uchar_t* hn8  = base + 1310720;               // 2 x 4096 x 512 fp8
  uchar_t* qk8  = base + 5505024;               // 2 x 4096 x 1024 fp8 (q | k)
  uchar_t* vC8  = base + 13893632;              // 2 x 512 x 4096 fp8
  ushort_t* OT  = (ushort_t*)(base + 18087936); // 2 x 4096 x 512 bf16
  uchar_t* S8   = base + 26476544;              // 2 x 4096 x 4096 fp8 (P'=exp/16)
  float* fbuf   = (float*)(base + 60030976);
  float* stats  = fbuf;                // 128
  float* stats2 = fbuf + 128;          // 128
  float* qkbias = fbuf + 256;          // 1024
  float* l      = fbuf + 1280;         // 8192 row sums

  const long long HS8 = 2097152;  // 4096*512 per batch
  const long long QS8 = 4194304;  // 4096*1024 per batch
  const long long SS8 = 16777216; // 4096*4096 per batch
  const float scale = 0.044194173824159216f;  // 512^-0.5

  cvt_weights<<<dim3(1061), dim3(256), 0, stream>>>(
      wq, wk, wv, wo, bq, bk, wqk8, wv8, wob, qkbias, stats2, l);
  gn_stats_partial<<<dim3(256), dim3(256), 0, stream>>>(x, stats2);
  gn_finalize<<<dim3(1), dim3(64), 0, stream>>>(stats2, stats);
  gn_apply<<<dim3(128, 16, 2), dim3(32, 8), 0, stream>>>(x, gamma, beta, stats, hn8);
  // qk8 = hn8 * [wq;wk]^T (M=4096, N=1024, K=512), col bias, fp8 out
  gemm_fp8<64><<<dim3(16, 32, 2), dim3(256), 0, stream>>>(
      hn8, HS8, 512, wqk8, 0, 512, 512, 1024, qk8, QS8,
      qkbias, 2, 1.f, nullptr, 1, 3);
  // vC8 = wv8 * hn8^T (M=512, N=4096, K=512), row bias, fp8 out
  gemm_fp8<64><<<dim3(64, 4, 2), dim3(256), 0, stream>>>(
      wv8, 0, 512, hn8, HS8, 512, 512, 4096, vC8, HS8,
      bv, 1, 1.f, nullptr, 0, 3);
  // P' = exp(scale * q*k^T)/16 fp8 + fused row sums (M=N=4096, K=512)
  gemm_fp8<64><<<dim3(64, 32, 2), dim3(256), 0, stream>>>(
      qk8, QS8, 1024, qk8 + 512, QS8, 1024, 512, 4096, S8, SS8,
      nullptr, 0, scale, l, 1, 2);
  // OT = P' * vC8^T (M=4096, N=512, K=4096), bf16 out
  gemm_fp8<64><<<dim3(8, 32, 2), dim3(256), 0, stream>>>(
      S8, SS8, 4096, vC8, HS8, 4096, 4096, 512, OT, HS8,
      nullptr, 0, 1.f, nullptr, 1, 0);
  // y = wo * (OT/l)^T + bo + x (M=512, N=4096, K=512), fp32 + residual
  gemm_abt<64><<<dim3(64, 4, 2), dim3(256), 0, stream>>>(
      wob, 0, 512, OT, HS8, 512, 512, 4096, 4096, nullptr, HS8, bo, 1, 1.f,
      out, x, nullptr, l, 0, 1);
}